// Round 1
// baseline (902.073 us; speedup 1.0000x reference)
//
#include <hip/hip_runtime.h>

// Problem constants (fixed by setup_inputs): B=64 samples, C=50 parts, N=65536 points.
#define BB 64
#define CC 50
#define NN 65536

// ShapeNet class -> contiguous part-id range boundaries.
__constant__ int c_starts[17] = {0, 4, 6, 8, 12, 16, 19, 22, 24, 28, 30, 36, 38, 41, 44, 47, 50};

// Main kernel: masked argmax over the class's valid part range + per-(b,part)
// histograms (inter / pred_cnt / gt_cnt) via LDS atomics -> global atomics.
// Grid: B * 64 chunks; block = 256 threads; each thread owns 4 consecutive n.
__global__ __launch_bounds__(256) void miou_main(
    const float* __restrict__ logits,   // [B, C, N]
    const int*   __restrict__ targets,  // [B, N]
    const int*   __restrict__ cls,      // [B]
    float*       __restrict__ out,      // [1 + B*N]: out[0]=mean iou (written later), out[1..]=pred
    int*         __restrict__ cnt)      // [3][B][C]: inter, pred_cnt, gt_cnt
{
    __shared__ int s_cnt[3 * CC];
    const int b     = (int)blockIdx.x >> 6;   // 64 chunks per sample
    const int chunk = (int)blockIdx.x & 63;

    for (int i = threadIdx.x; i < 3 * CC; i += 256) s_cnt[i] = 0;
    __syncthreads();

    const int cl = cls[b];                    // wave-uniform broadcast load
    const int s0 = c_starts[cl];
    const int s1 = c_starts[cl + 1];

    const int n0 = (chunk << 10) + ((int)threadIdx.x << 2);   // 1024 n per block
    const float* lg = logits + (size_t)b * (size_t)CC * NN;

    const int4 tgt = *(const int4*)(targets + (size_t)b * NN + n0);

    // argmax over c in [s0, s1): ascending c, strict '>' keeps FIRST max
    // (matches jnp.argmax tie-breaking).
    float4 best = *(const float4*)(lg + (size_t)s0 * NN + n0);
    int bx = s0, by = s0, bz = s0, bw = s0;
    for (int c = s0 + 1; c < s1; ++c) {
        float4 v = *(const float4*)(lg + (size_t)c * NN + n0);
        if (v.x > best.x) { best.x = v.x; bx = c; }
        if (v.y > best.y) { best.y = v.y; by = c; }
        if (v.z > best.z) { best.z = v.z; bz = c; }
        if (v.w > best.w) { best.w = v.w; bw = c; }
    }

    // pred output as float32 (d_out is float; offset 1 breaks 16B alignment,
    // so 4 scalar stores — still a contiguous 1 KiB span per wave).
    float* po = out + 1 + (size_t)b * NN + n0;
    po[0] = (float)bx; po[1] = (float)by; po[2] = (float)bz; po[3] = (float)bw;

    // Histograms: pred_cnt (bins limited to [s0,s1)), gt_cnt (full [0,50)),
    // inter (pred==target).
    atomicAdd(&s_cnt[CC + bx], 1);
    atomicAdd(&s_cnt[CC + by], 1);
    atomicAdd(&s_cnt[CC + bz], 1);
    atomicAdd(&s_cnt[CC + bw], 1);
    atomicAdd(&s_cnt[2 * CC + tgt.x], 1);
    atomicAdd(&s_cnt[2 * CC + tgt.y], 1);
    atomicAdd(&s_cnt[2 * CC + tgt.z], 1);
    atomicAdd(&s_cnt[2 * CC + tgt.w], 1);
    if (bx == tgt.x) atomicAdd(&s_cnt[bx], 1);
    if (by == tgt.y) atomicAdd(&s_cnt[by], 1);
    if (bz == tgt.z) atomicAdd(&s_cnt[bz], 1);
    if (bw == tgt.w) atomicAdd(&s_cnt[bw], 1);

    __syncthreads();
    for (int i = threadIdx.x; i < 3 * CC; i += 256) {
        int v = s_cnt[i];
        if (v) atomicAdd(&cnt[(i / CC) * (BB * CC) + b * CC + (i % CC)], v);
    }
}

// Finalize: one wave, lane b = sample b. IoU over valid parts, then wave
// shuffle-reduce to the scalar mean.
__global__ __launch_bounds__(64) void miou_final(
    const int* __restrict__ cls,
    const int* __restrict__ cnt,
    float*     __restrict__ out)
{
    const int b  = threadIdx.x;
    const int cl = cls[b];
    const int s0 = c_starts[cl], s1 = c_starts[cl + 1];
    float sum = 0.f;
    for (int c = s0; c < s1; ++c) {
        float inter = (float)cnt[b * CC + c];
        float pc    = (float)cnt[BB * CC + b * CC + c];
        float gc    = (float)cnt[2 * BB * CC + b * CC + c];
        float un    = pc + gc - inter;
        float iou   = (un == 0.f) ? 1.f : inter / fmaxf(un, 1.f);
        sum += iou;
    }
    float biou = sum / (float)(s1 - s0);
    for (int off = 32; off; off >>= 1) biou += __shfl_down(biou, off);
    if (b == 0) out[0] = biou / (float)BB;
}

extern "C" void kernel_launch(void* const* d_in, const int* in_sizes, int n_in,
                              void* d_out, int out_size, void* d_ws, size_t ws_size,
                              hipStream_t stream) {
    const float* logits  = (const float*)d_in[0];
    const int*   targets = (const int*)d_in[1];
    const int*   cls     = (const int*)d_in[2];
    float*       out     = (float*)d_out;
    int*         cnt     = (int*)d_ws;

    // counts workspace is re-poisoned to 0xAA before every launch — zero it.
    hipMemsetAsync(cnt, 0, 3 * BB * CC * sizeof(int), stream);

    miou_main<<<dim3(BB * 64), dim3(256), 0, stream>>>(logits, targets, cls, out, cnt);
    miou_final<<<1, 64, 0, stream>>>(cls, cnt, out);
}